// Round 2
// baseline (1219.584 us; speedup 1.0000x reference)
//
#include <hip/hip_runtime.h>

#define N_IN   128
#define N_HID  15
#define N_HIDP 16
#define N_OUT  32

// ---------------------------------------------------------------------------
// Detect int64 vs int32 edge payload: if int64, every odd 32-bit word (high
// word of a value < 2^31) is 0.
// ---------------------------------------------------------------------------
__global__ void detect_kernel(const int* __restrict__ idx, int* __restrict__ flag) {
    __shared__ int nz;
    if (threadIdx.x == 0) nz = 0;
    __syncthreads();
    if (idx[2 * threadIdx.x + 1] != 0) atomicOr(&nz, 1);
    __syncthreads();
    if (threadIdx.x == 0) *flag = (nz == 0) ? 1 : 0;
}

// Convert edges to int32 and count in-degree (excluding self-loops).
__global__ void convert_kernel(const void* __restrict__ idx, int E,
                               int* __restrict__ src32, int* __restrict__ dst32,
                               unsigned* __restrict__ deg,
                               const int* __restrict__ flag) {
    int e = blockIdx.x * 256 + threadIdx.x;
    if (e >= E) return;
    int s, d;
    if (*flag) {
        const long long* p = (const long long*)idx;
        s = (int)p[e];
        d = (int)p[E + e];
    } else {
        const int* p = (const int*)idx;
        s = p[e];
        d = p[E + e];
    }
    src32[e] = s;
    dst32[e] = d;
    atomicAdd(&deg[d], 1u);
}

// ---------------------------------------------------------------------------
// Exclusive scan of deg -> rowstart (3 kernels), fused dinv + cursor init.
// ---------------------------------------------------------------------------
__global__ __launch_bounds__(1024) void scan1_kernel(const unsigned* __restrict__ deg,
                                                     int N, int* __restrict__ incl,
                                                     int* __restrict__ part) {
    __shared__ int sh[1024];
    int i = blockIdx.x * 1024 + threadIdx.x;
    int v = (i < N) ? (int)deg[i] : 0;
    sh[threadIdx.x] = v;
    __syncthreads();
#pragma unroll
    for (int off = 1; off < 1024; off <<= 1) {
        int t = (threadIdx.x >= off) ? sh[threadIdx.x - off] : 0;
        __syncthreads();
        sh[threadIdx.x] += t;
        __syncthreads();
    }
    if (i < N) incl[i] = sh[threadIdx.x];
    if (threadIdx.x == 1023) part[blockIdx.x] = sh[1023];
}

__global__ __launch_bounds__(1024) void scan2_kernel(int* __restrict__ part, int nb) {
    __shared__ int sh[1024];
    int v = (threadIdx.x < nb) ? part[threadIdx.x] : 0;
    sh[threadIdx.x] = v;
    __syncthreads();
#pragma unroll
    for (int off = 1; off < 1024; off <<= 1) {
        int t = (threadIdx.x >= off) ? sh[threadIdx.x - off] : 0;
        __syncthreads();
        sh[threadIdx.x] += t;
        __syncthreads();
    }
    if (threadIdx.x < nb) part[threadIdx.x] = sh[threadIdx.x] - v;  // exclusive
}

__global__ __launch_bounds__(1024) void scan3_kernel(const int* __restrict__ incl,
                                                     const unsigned* __restrict__ deg,
                                                     const int* __restrict__ part,
                                                     int N, int E,
                                                     int* __restrict__ rowstart,
                                                     int* __restrict__ cursor,
                                                     float* __restrict__ dinv) {
    int i = blockIdx.x * 1024 + threadIdx.x;
    if (i < N) {
        int ex = incl[i] - (int)deg[i] + part[i >> 10];
        rowstart[i] = ex;
        cursor[i] = ex;
        dinv[i] = rsqrtf((float)deg[i] + 1.0f);  // +1 = self-loop
    }
    if (i == 0) rowstart[N] = E;
}

// Fill CSR: csr[slot in dst's row] = src.
__global__ void fill_kernel(const int* __restrict__ src, const int* __restrict__ dst,
                            int E, int* __restrict__ cursor, int* __restrict__ csr) {
    int e = blockIdx.x * 256 + threadIdx.x;
    if (e >= E) return;
    int pos = atomicAdd(&cursor[dst[e]], 1);
    csr[pos] = src[e];
}

// ---------------------------------------------------------------------------
// GEMM1: hs[i][c] = (x[i] @ W1[:,c]) * dinv[i], padded to 16 ch (ch15 = 0).
// ---------------------------------------------------------------------------
__global__ __launch_bounds__(256) void gemm1_kernel(
    const float* __restrict__ x, const float* __restrict__ W1,
    const float* __restrict__ dinv, float* __restrict__ hs, int N) {
    __shared__ float Wl[N_IN * N_HIDP];
    for (int i = threadIdx.x; i < N_IN * N_HIDP; i += 256) {
        int k = i >> 4, c = i & 15;
        Wl[i] = (c < N_HID) ? W1[k * N_HID + c] : 0.f;
    }
    __syncthreads();
    const float4* __restrict__ Wl4 = (const float4*)Wl;
    const float4* __restrict__ x4  = (const float4*)x;

    int r0 = blockIdx.x * 512 + threadIdx.x;
    int r1 = r0 + 256;
    int r0c = r0 < N ? r0 : N - 1;
    int r1c = r1 < N ? r1 : N - 1;

    float acc0[16], acc1[16];
#pragma unroll
    for (int c = 0; c < 16; ++c) { acc0[c] = 0.f; acc1[c] = 0.f; }

    for (int k4 = 0; k4 < 32; ++k4) {
        float4 xv0 = x4[r0c * 32 + k4];
        float4 xv1 = x4[r1c * 32 + k4];
        float xs0[4] = {xv0.x, xv0.y, xv0.z, xv0.w};
        float xs1[4] = {xv1.x, xv1.y, xv1.z, xv1.w};
#pragma unroll
        for (int t = 0; t < 4; ++t) {
            int k = k4 * 4 + t;
            float4 wa = Wl4[k * 4 + 0];
            float4 wb = Wl4[k * 4 + 1];
            float4 wc = Wl4[k * 4 + 2];
            float4 wd = Wl4[k * 4 + 3];
            float wf[16] = {wa.x, wa.y, wa.z, wa.w, wb.x, wb.y, wb.z, wb.w,
                            wc.x, wc.y, wc.z, wc.w, wd.x, wd.y, wd.z, wd.w};
#pragma unroll
            for (int c = 0; c < 16; ++c) {
                acc0[c] = fmaf(xs0[t], wf[c], acc0[c]);
                acc1[c] = fmaf(xs1[t], wf[c], acc1[c]);
            }
        }
    }
    float4* __restrict__ hs4 = (float4*)hs;
    if (r0 < N) {
        float di = dinv[r0];
#pragma unroll
        for (int j = 0; j < 4; ++j)
            hs4[r0 * 4 + j] = make_float4(acc0[4*j]*di, acc0[4*j+1]*di,
                                          acc0[4*j+2]*di, acc0[4*j+3]*di);
    }
    if (r1 < N) {
        float di = dinv[r1];
#pragma unroll
        for (int j = 0; j < 4; ++j)
            hs4[r1 * 4 + j] = make_float4(acc1[4*j]*di, acc1[4*j+1]*di,
                                          acc1[4*j+2]*di, acc1[4*j+3]*di);
    }
}

// ---------------------------------------------------------------------------
// agg1: per-node gather-sum over CSR + fused finalize1.
// 16 lanes per node (lane = channel), 16 nodes per 256-thread block.
// hs2[i][c] = relu(dinv[i]*(sum_in + hs[i][c]) + b1[c]) * dinv[i]
// ---------------------------------------------------------------------------
__global__ __launch_bounds__(256) void agg1_kernel(
    const int* __restrict__ rowstart, const int* __restrict__ csr,
    const float* __restrict__ hs, const float* __restrict__ dinv,
    const float* __restrict__ b1, float* __restrict__ hs2, int N) {
    int c = threadIdx.x & 15;
    int i = blockIdx.x * 16 + (threadIdx.x >> 4);
    int iw = i < N ? i : N - 1;

    int s0 = rowstart[iw], s1 = rowstart[iw + 1];
    float acc = hs[iw * N_HIDP + c];  // self-loop
    int j = s0;
    for (; j + 4 <= s1; j += 4) {
        int e0 = csr[j], e1 = csr[j + 1], e2 = csr[j + 2], e3 = csr[j + 3];
        float a0 = hs[e0 * N_HIDP + c];
        float a1 = hs[e1 * N_HIDP + c];
        float a2 = hs[e2 * N_HIDP + c];
        float a3 = hs[e3 * N_HIDP + c];
        acc += (a0 + a1) + (a2 + a3);
    }
    for (; j < s1; ++j) acc += hs[csr[j] * N_HIDP + c];

    if (i < N) {
        float di = dinv[i];
        float b = (c < N_HID) ? b1[c] : 0.f;
        float v = fmaxf(di * acc + b, 0.f);
        hs2[i * N_HIDP + c] = v * di;
    }
}

// ---------------------------------------------------------------------------
// agg2: per-node gather-sum + fused (@W2 + b2) epilogue through LDS.
// ---------------------------------------------------------------------------
__global__ __launch_bounds__(256) void agg2_kernel(
    const int* __restrict__ rowstart, const int* __restrict__ csr,
    const float* __restrict__ hs2, const float* __restrict__ dinv,
    const float* __restrict__ W2, const float* __restrict__ b2,
    float* __restrict__ out, int N) {
    __shared__ float W2l[N_HIDP * N_OUT];   // [c][o], c=15 padded zero
    __shared__ float ubuf[16][N_HIDP];      // 16 nodes x 16 channels
    for (int t = threadIdx.x; t < N_HIDP * N_OUT; t += 256)
        W2l[t] = (t < N_HID * N_OUT) ? W2[t] : 0.f;

    int c = threadIdx.x & 15;
    int q = threadIdx.x >> 4;               // local node 0..15
    int i = blockIdx.x * 16 + q;
    int iw = i < N ? i : N - 1;

    int s0 = rowstart[iw], s1 = rowstart[iw + 1];
    float acc = hs2[iw * N_HIDP + c];       // self-loop
    int j = s0;
    for (; j + 4 <= s1; j += 4) {
        int e0 = csr[j], e1 = csr[j + 1], e2 = csr[j + 2], e3 = csr[j + 3];
        float a0 = hs2[e0 * N_HIDP + c];
        float a1 = hs2[e1 * N_HIDP + c];
        float a2 = hs2[e2 * N_HIDP + c];
        float a3 = hs2[e3 * N_HIDP + c];
        acc += (a0 + a1) + (a2 + a3);
    }
    for (; j < s1; ++j) acc += hs2[csr[j] * N_HIDP + c];

    ubuf[q][c] = dinv[iw] * acc;            // u[c]; c==15 -> 0 (hs2 pad col = 0)
    __syncthreads();

    // outputs o = c and o = c+16 for node q
    float a0 = b2[c], a1 = b2[c + 16];
#pragma unroll
    for (int k = 0; k < N_HID; ++k) {
        float uv = ubuf[q][k];
        a0 = fmaf(uv, W2l[k * N_OUT + c], a0);
        a1 = fmaf(uv, W2l[k * N_OUT + c + 16], a1);
    }
    if (i < N) {
        out[i * N_OUT + c] = a0;
        out[i * N_OUT + c + 16] = a1;
    }
}

// ---------------------------------------------------------------------------
extern "C" void kernel_launch(void* const* d_in, const int* in_sizes, int n_in,
                              void* d_out, int out_size, void* d_ws, size_t ws_size,
                              hipStream_t stream) {
    const float* x   = (const float*)d_in[0];
    const void*  eix = d_in[1];
    const float* W1  = (const float*)d_in[2];
    const float* b1  = (const float*)d_in[3];
    const float* W2  = (const float*)d_in[4];
    const float* b2  = (const float*)d_in[5];
    float* out = (float*)d_out;

    const int N = in_sizes[0] / N_IN;   // 200000
    const int E = in_sizes[1] / 2;      // 6400000

    char* ws = (char*)d_ws;
    size_t off = 0;
    auto alloc = [&](size_t bytes) -> void* {
        void* p = ws + off;
        off += (bytes + 255) & ~(size_t)255;
        return p;
    };
    int*      src32 = (int*)alloc((size_t)E * 4);
    int*      dst32 = (int*)alloc((size_t)E * 4);
    int*      csr   = (int*)alloc((size_t)E * 4);
    unsigned* deg   = (unsigned*)alloc((size_t)N * 4);
    int*      incl  = (int*)alloc((size_t)N * 4);
    int*      rowst = (int*)alloc((size_t)(N + 1) * 4);
    int*      curs  = (int*)alloc((size_t)N * 4);
    float*    dinv  = (float*)alloc((size_t)N * 4);
    float*    hs    = (float*)alloc((size_t)N * N_HIDP * 4);
    float*    hs2   = (float*)alloc((size_t)N * N_HIDP * 4);
    int*      part  = (int*)alloc(4096);
    int*      flag  = (int*)alloc(256);

    const int nscan = (N + 1023) / 1024;   // 196 blocks

    hipMemsetAsync(deg, 0, (size_t)N * 4, stream);

    detect_kernel<<<1, 256, 0, stream>>>((const int*)eix, flag);
    convert_kernel<<<(E + 255) / 256, 256, 0, stream>>>(eix, E, src32, dst32, deg, flag);
    scan1_kernel<<<nscan, 1024, 0, stream>>>(deg, N, incl, part);
    scan2_kernel<<<1, 1024, 0, stream>>>(part, nscan);
    scan3_kernel<<<nscan, 1024, 0, stream>>>(incl, deg, part, N, E, rowst, curs, dinv);
    fill_kernel<<<(E + 255) / 256, 256, 0, stream>>>(src32, dst32, E, curs, csr);

    gemm1_kernel<<<(N + 511) / 512, 256, 0, stream>>>(x, W1, dinv, hs, N);

    const int nagg = (N + 15) / 16;        // 12500 blocks
    agg1_kernel<<<nagg, 256, 0, stream>>>(rowst, csr, hs, dinv, b1, hs2, N);
    agg2_kernel<<<nagg, 256, 0, stream>>>(rowst, csr, hs2, dinv, W2, b2, out, N);
}